// Round 5
// baseline (108.643 us; speedup 1.0000x reference)
//
#include <hip/hip_runtime.h>

#define HIDDEN 64
#define SEQLEN 96
#define NB 10
#define BATCH 16384
#define NCLASS 2
#define KTOT (HIDDEN * NB)   // 640
#define NKC (KTOT / 32)      // 20 K-chunks of 32
#define MT 32                // batch rows per block (2 M-subtiles of 16)
#define NW 4                 // waves per block = K-split factor
#define KCW (NKC / NW)       // 5 K-chunks per wave
#define HSS 33               // hs stride (pad)
#define CRS 66               // Cred stride (pad)

typedef __attribute__((ext_vector_type(8))) short bf16x8;
typedef __attribute__((ext_vector_type(4))) float f32x4;

__device__ __forceinline__ float fast_tanh(float x) {
    float e = __expf(x + x);
    float r = __builtin_amdgcn_rcpf(e + 1.0f);
    return fmaf(-2.0f, r, 1.0f);
}

__device__ __forceinline__ unsigned bf16_rn(float f) {
    unsigned u = __float_as_uint(f);
    return (u + 0x8000u) >> 16;
}

// Repack one 32-wide o-half of Wc (fp32, layout (i,o,k)) into LDS bf16
// B-fragments for mfma_16x16x32: Wp[((kcg*2+ntl)*64 + lhi*16 + n)*8 + j],
// where q = kcg*32 + lhi*8 + j = i*10 + k, o = half*32 + ntl*16 + n.
// Source rows are contiguous 320-float runs per i -> float4 loads.
__device__ __forceinline__ void repack_half(const float* __restrict__ Wc,
                                            ushort* Wp_lds, int tid, int half) {
    const int i    = tid >> 2;          // 64 i's, 4 threads each
    const int part = tid & 3;           // 8 o's per thread
    const float* src = Wc + i * (HIDDEN * NB) + half * (32 * NB) + part * 80;
    unsigned* Wp32 = (unsigned*)Wp_lds;
#pragma unroll
    for (int hp = 0; hp < 2; ++hp) {    // two 40-float (4 o-row) passes
        float fv[40];
#pragma unroll
        for (int v = 0; v < 10; ++v)
            *(float4*)(fv + 4 * v) = *(const float4*)(src + hp * 40 + 4 * v);
#pragma unroll
        for (int ro = 0; ro < 4; ++ro) {
            const int oo  = part * 8 + hp * 4 + ro;   // o-local in half [0,32)
            const int ntl = oo >> 4, n = oo & 15;
#pragma unroll
            for (int kk = 0; kk < 5; ++kk) {          // pairs (k, k+1), k even
                const int k   = 2 * kk;
                const int q   = i * NB + k;           // even -> j even
                const int kcg = q >> 5;
                const int lhi = (q >> 3) & 3;
                const int j   = q & 7;
                const unsigned val = bf16_rn(fv[ro * 10 + k]) |
                                     (bf16_rn(fv[ro * 10 + k + 1]) << 16);
                Wp32[((((kcg * 2 + ntl) * 64) + lhi * 16 + n) * 8 + j) >> 1] = val;
            }
        }
    }
}

__global__ __launch_bounds__(256, 2) void kan_one(
    const float* __restrict__ x,    // (B, SEQLEN)
    const float* __restrict__ Wx,   // (1, HIDDEN, NB)
    const float* __restrict__ ax, const float* __restrict__ cx,  // (1, NB)
    const float* __restrict__ Wc,   // (HIDDEN, HIDDEN, NB)
    const float* __restrict__ ac,   // (HIDDEN, NB) flat == q-order
    const float* __restrict__ cc,   // (HIDDEN, NB)
    const float* __restrict__ Wout, // (HIDDEN, NCLASS)
    float* __restrict__ out)        // (B, NCLASS)
{
    __shared__ ushort Wp[NKC * 2 * 64 * 8];   // one o-half of B-frags: 40 KB
    __shared__ float hs[65 * HSS];            // h[i][m] + guard row
    __shared__ float Cred[MT * CRS];          // K-split reduction
    __shared__ float outb[MT * NCLASS];

    const int lane = threadIdx.x;    // 0..63
    const int w    = threadIdx.y;    // 0..3 (K-split wave id)
    const int tid  = w * 64 + lane;
    const int bb   = blockIdx.x * MT;

    for (int idx = tid; idx < MT * CRS; idx += 256) Cred[idx] = 0.0f;

    // ---- phase 0: repack o-half 0 + stage A (h from x[:,95]; recurrence dead)
    repack_half(Wc, Wp, tid, 0);
    {
        const int sm = tid & 31;     // batch row
        const int sg = tid >> 5;     // 8 i's per thread
        const float u = x[(bb + sm) * SEQLEN + (SEQLEN - 1)];
        float t[NB];
#pragma unroll
        for (int k = 0; k < NB; ++k)
            t[k] = fast_tanh(fmaf(ax[k], u, cx[k]));
#pragma unroll
        for (int r = 0; r < 8; ++r) {
            const int i = sg * 8 + r;
            const float* wxr = Wx + i * NB;
            float hx = 0.0f;
#pragma unroll
            for (int k = 0; k < NB; ++k)
                hx = fmaf(wxr[k], t[k], hx);
            hs[i * HSS + sm] = fast_tanh(hx);
        }
    }
    __syncthreads();

    // ---- GEMM half 0 (o in [0,32)): build P packs once, cache in regs ----
    const int m    = lane & 15;
    const int quad = lane >> 4;
    bf16x8 afs0[KCW], afs1[KCW];     // cached A-frag packs, msub 0 / 1
    f32x4 A00 = {0,0,0,0}, A01 = {0,0,0,0}, A10 = {0,0,0,0}, A11 = {0,0,0,0};
    f32x4 B00 = {0,0,0,0}, B01 = {0,0,0,0}, B10 = {0,0,0,0}, B11 = {0,0,0,0};

#pragma unroll
    for (int c = 0; c < KCW; ++c) {
        const int kcg = w * KCW + c;
        const int q0  = kcg * 32 + quad * 8;
        const int i0  = q0 / 10;
        const int r0  = q0 - i0 * 10;
        const float h0a = hs[i0 * HSS + m];
        const float h1a = hs[(i0 + 1) * HSS + m];        // guard row, never OOB
        const float h0b = hs[i0 * HSS + 16 + m];
        const float h1b = hs[(i0 + 1) * HSS + 16 + m];
        const float4 av0 = *(const float4*)(ac + q0);
        const float4 av1 = *(const float4*)(ac + q0 + 4);
        const float4 cv0 = *(const float4*)(cc + q0);
        const float4 cv1 = *(const float4*)(cc + q0 + 4);
        const float av[8] = {av0.x,av0.y,av0.z,av0.w,av1.x,av1.y,av1.z,av1.w};
        const float cv[8] = {cv0.x,cv0.y,cv0.z,cv0.w,cv1.x,cv1.y,cv1.z,cv1.w};

        union { unsigned u[4]; bf16x8 v; } af0, af1;
#pragma unroll
        for (int jj = 0; jj < 4; ++jj) {
            const int j0 = 2 * jj, j1 = 2 * jj + 1;
            const float hA0 = (r0 + j0 >= 10) ? h1a : h0a;
            const float hA1 = (r0 + j1 >= 10) ? h1a : h0a;
            const float hB0 = (r0 + j0 >= 10) ? h1b : h0b;
            const float hB1 = (r0 + j1 >= 10) ? h1b : h0b;
            const float pA0 = fast_tanh(fmaf(av[j0], hA0, cv[j0]));
            const float pA1 = fast_tanh(fmaf(av[j1], hA1, cv[j1]));
            const float pB0 = fast_tanh(fmaf(av[j0], hB0, cv[j0]));
            const float pB1 = fast_tanh(fmaf(av[j1], hB1, cv[j1]));
            af0.u[jj] = bf16_rn(pA0) | (bf16_rn(pA1) << 16);
            af1.u[jj] = bf16_rn(pB0) | (bf16_rn(pB1) << 16);
        }
        afs0[c] = af0.v;
        afs1[c] = af1.v;

        const ushort* wb = Wp + (size_t)(kcg * 2) * 512 + lane * 8;
        const bf16x8 b0 = *(const bf16x8*)(wb);
        const bf16x8 b1 = *(const bf16x8*)(wb + 512);
        A00 = __builtin_amdgcn_mfma_f32_16x16x32_bf16(af0.v, b0, A00, 0, 0, 0);
        A01 = __builtin_amdgcn_mfma_f32_16x16x32_bf16(af0.v, b1, A01, 0, 0, 0);
        A10 = __builtin_amdgcn_mfma_f32_16x16x32_bf16(af1.v, b0, A10, 0, 0, 0);
        A11 = __builtin_amdgcn_mfma_f32_16x16x32_bf16(af1.v, b1, A11, 0, 0, 0);
    }
    __syncthreads();                 // all waves done reading Wp half 0

    // ---- repack o-half 1, then GEMM half 1 reusing cached P packs ----
    repack_half(Wc, Wp, tid, 1);
    __syncthreads();

#pragma unroll
    for (int c = 0; c < KCW; ++c) {
        const int kcg = w * KCW + c;
        const ushort* wb = Wp + (size_t)(kcg * 2) * 512 + lane * 8;
        const bf16x8 b0 = *(const bf16x8*)(wb);
        const bf16x8 b1 = *(const bf16x8*)(wb + 512);
        B00 = __builtin_amdgcn_mfma_f32_16x16x32_bf16(afs0[c], b0, B00, 0, 0, 0);
        B01 = __builtin_amdgcn_mfma_f32_16x16x32_bf16(afs0[c], b1, B01, 0, 0, 0);
        B10 = __builtin_amdgcn_mfma_f32_16x16x32_bf16(afs1[c], b0, B10, 0, 0, 0);
        B11 = __builtin_amdgcn_mfma_f32_16x16x32_bf16(afs1[c], b1, B11, 0, 0, 0);
    }

    // ---- K-split combine; C/D layout: col=lane&15, row=quad*4+reg ----
#pragma unroll
    for (int reg = 0; reg < 4; ++reg) {
        const int row = quad * 4 + reg;
        atomicAdd(&Cred[(row)      * CRS +  0 + m], A00[reg]);
        atomicAdd(&Cred[(row)      * CRS + 16 + m], A01[reg]);
        atomicAdd(&Cred[(row + 16) * CRS +  0 + m], A10[reg]);
        atomicAdd(&Cred[(row + 16) * CRS + 16 + m], A11[reg]);
        atomicAdd(&Cred[(row)      * CRS + 32 + m], B00[reg]);
        atomicAdd(&Cred[(row)      * CRS + 48 + m], B01[reg]);
        atomicAdd(&Cred[(row + 16) * CRS + 32 + m], B10[reg]);
        atomicAdd(&Cred[(row + 16) * CRS + 48 + m], B11[reg]);
    }
    __syncthreads();

    // ---- epilogue: g = tanh(C), out = g @ Wout ----
    {
        const int mm = tid >> 3;         // batch row 0..31
        const int ob = (tid & 7) * 8;    // 8 o's per thread
        float r0 = 0.0f, r1 = 0.0f;
#pragma unroll
        for (int t2 = 0; t2 < 8; ++t2) {
            const int o = ob + t2;
            const float g = fast_tanh(Cred[mm * CRS + o]);
            r0 = fmaf(g, Wout[o * NCLASS + 0], r0);
            r1 = fmaf(g, Wout[o * NCLASS + 1], r1);
        }
#pragma unroll
        for (int off = 4; off > 0; off >>= 1) {
            r0 += __shfl_down(r0, off, 8);
            r1 += __shfl_down(r1, off, 8);
        }
        if ((tid & 7) == 0) {
            outb[mm * NCLASS + 0] = r0;
            outb[mm * NCLASS + 1] = r1;
        }
    }
    __syncthreads();
    if (tid < MT * NCLASS)
        out[bb * NCLASS + tid] = outb[tid];   // coalesced 64-dword store
}

extern "C" void kernel_launch(void* const* d_in, const int* in_sizes, int n_in,
                              void* d_out, int out_size, void* d_ws, size_t ws_size,
                              hipStream_t stream) {
    const float* x    = (const float*)d_in[0];
    const float* Wx   = (const float*)d_in[1];
    const float* ax   = (const float*)d_in[2];
    const float* cx   = (const float*)d_in[3];
    // d_in[4..6] = Wh, ah, ch — dead (comb[:, :HIDDEN] == tanh(x_phi))
    const float* Wc   = (const float*)d_in[7];
    const float* ac   = (const float*)d_in[8];
    const float* cc   = (const float*)d_in[9];
    const float* Wout = (const float*)d_in[10];
    float* out = (float*)d_out;

    // Single kernel, single graph node; d_ws unused.
    kan_one<<<dim3(BATCH / MT), dim3(64, NW), 0, stream>>>(
        x, Wx, ax, cx, Wc, ac, cc, Wout, out);
}

// Round 6
// 84.301 us; speedup vs baseline: 1.2888x; 1.2888x over previous
//
#include <hip/hip_runtime.h>

#define HIDDEN 64
#define SEQLEN 96
#define NB 10
#define BATCH 16384
#define NCLASS 2
#define KTOT (HIDDEN * NB)   // 640
#define NKC (KTOT / 32)      // 20 K-chunks of 32
#define MT 16                // batch rows per block (one MFMA M-tile)
#define NW 5                 // waves per block = K-split factor
#define KCW (NKC / NW)       // 4 K-chunks per wave
#define HSS 17               // hs stride (16+1: kills 4-way quad conflict)
#define CRS 66               // Cred stride (64+2)

typedef __attribute__((ext_vector_type(8))) short bf16x8;
typedef __attribute__((ext_vector_type(4))) float f32x4;

__device__ __forceinline__ float fast_tanh(float x) {
    float e = __expf(x + x);
    float r = __builtin_amdgcn_rcpf(e + 1.0f);
    return fmaf(-2.0f, r, 1.0f);
}

__device__ __forceinline__ unsigned bf16_rn(float f) {
    unsigned u = __float_as_uint(f);
    return (u + 0x8000u) >> 16;
}

// Repack Wc (i,o,k) fp32 -> bf16 B-fragments in d_ws. COALESCED reads
// (thread e reads Wc[e]), scattered ushort writes (L2-absorbed).
// Wp[((kcg*4 + nt)*64 + lhi*16 + n)*8 + j], q=i*10+k: kcg=q>>5,
// lhi=(q>>3)&3, j=q&7; o: nt=o>>4, n=o&15.
__global__ __launch_bounds__(256) void prep_wb(const float* __restrict__ Wc,
                                               ushort* __restrict__ Wp) {
    const int e = blockIdx.x * 256 + threadIdx.x;   // 0..40959
    const float v = Wc[e];
    const int i   = e / 640;
    const int rem = e - i * 640;
    const int o   = rem / 10;
    const int k   = rem - o * 10;
    const int q   = i * NB + k;
    const int kcg = q >> 5, lhi = (q >> 3) & 3, j = q & 7;
    const int nt  = o >> 4, n = o & 15;
    Wp[(((kcg * 4 + nt) * 64) + lhi * 16 + n) * 8 + j] = (ushort)bf16_rn(v);
}

__global__ __launch_bounds__(64 * NW, 5) void kan_mfma(
    const float* __restrict__ x,    // (B, SEQLEN)
    const float* __restrict__ Wx,   // (1, HIDDEN, NB)
    const float* __restrict__ ax, const float* __restrict__ cx,  // (1, NB)
    const float* __restrict__ ac,   // (HIDDEN, NB) flat == q-order
    const float* __restrict__ cc,   // (HIDDEN, NB)
    const float* __restrict__ Wout, // (HIDDEN, NCLASS)
    const ushort* __restrict__ Wp,  // packed B-fragments (d_ws)
    float* __restrict__ out)        // (B, NCLASS)
{
    __shared__ float hs[65 * HSS];          // h[i][m] + guard row (4.4 KB)
    __shared__ float Cred[NW][MT * CRS];    // per-wave partials (21 KB) - no atomics
    __shared__ float outb[MT * NCLASS];

    const int lane = threadIdx.x;    // 0..63
    const int w    = threadIdx.y;    // 0..4 (K-split wave id)
    const int tid  = w * 64 + lane;
    const int bb   = blockIdx.x * MT;

    // ---- stage A (first 4 waves): h from x[:,95]; recurrence is dead ----
    if (tid < 256) {
        const int sm = tid & 15;     // batch row
        const int sg = tid >> 4;     // 4 i's per thread
        const float u = x[(bb + sm) * SEQLEN + (SEQLEN - 1)];
        float t[NB];
#pragma unroll
        for (int k = 0; k < NB; ++k)
            t[k] = fast_tanh(fmaf(ax[k], u, cx[k]));
#pragma unroll
        for (int r = 0; r < 4; ++r) {
            const int i = sg * 4 + r;
            const float* wxr = Wx + i * NB;
            float hx = 0.0f;
#pragma unroll
            for (int k = 0; k < NB; ++k)
                hx = fmaf(wxr[k], t[k], hx);
            hs[i * HSS + sm] = fast_tanh(hx);
        }
    }
    __syncthreads();

    // ---- GEMM: wave w owns K-chunks [w*4, w*4+4), all 64 o ----
    const int m    = lane & 15;
    const int quad = lane >> 4;
    f32x4 a0 = {0,0,0,0}, a1 = {0,0,0,0}, a2 = {0,0,0,0}, a3 = {0,0,0,0};

#pragma unroll 1                     // compact body; 4 iterations
    for (int c = 0; c < KCW; ++c) {
        const int kcg = w * KCW + c;
        const int q0  = kcg * 32 + quad * 8;
        // issue all loads up front
        const ushort* wb = Wp + (size_t)(kcg * 4) * 512 + lane * 8;
        const bf16x8 b0 = *(const bf16x8*)(wb);
        const bf16x8 b1 = *(const bf16x8*)(wb + 512);
        const bf16x8 b2 = *(const bf16x8*)(wb + 1024);
        const bf16x8 b3 = *(const bf16x8*)(wb + 1536);
        const float4 av0 = *(const float4*)(ac + q0);
        const float4 av1 = *(const float4*)(ac + q0 + 4);
        const float4 cv0 = *(const float4*)(cc + q0);
        const float4 cv1 = *(const float4*)(cc + q0 + 4);
        const int i0 = q0 / 10;      // magic-mul
        const int r0 = q0 - i0 * 10;
        const float h0 = hs[i0 * HSS + m];
        const float h1 = hs[(i0 + 1) * HSS + m];  // guard row; never selected OOB

        const float av[8] = {av0.x,av0.y,av0.z,av0.w,av1.x,av1.y,av1.z,av1.w};
        const float cv[8] = {cv0.x,cv0.y,cv0.z,cv0.w,cv1.x,cv1.y,cv1.z,cv1.w};
        union { unsigned u[4]; bf16x8 v; } af;
#pragma unroll
        for (int jj = 0; jj < 4; ++jj) {
            const int j0 = 2 * jj, j1 = j0 + 1;
            const float hj0 = (r0 + j0 >= 10) ? h1 : h0;
            const float hj1 = (r0 + j1 >= 10) ? h1 : h0;
            const float p0 = fast_tanh(fmaf(av[j0], hj0, cv[j0]));
            const float p1 = fast_tanh(fmaf(av[j1], hj1, cv[j1]));
            af.u[jj] = bf16_rn(p0) | (bf16_rn(p1) << 16);
        }
        a0 = __builtin_amdgcn_mfma_f32_16x16x32_bf16(af.v, b0, a0, 0, 0, 0);
        a1 = __builtin_amdgcn_mfma_f32_16x16x32_bf16(af.v, b1, a1, 0, 0, 0);
        a2 = __builtin_amdgcn_mfma_f32_16x16x32_bf16(af.v, b2, a2, 0, 0, 0);
        a3 = __builtin_amdgcn_mfma_f32_16x16x32_bf16(af.v, b3, a3, 0, 0, 0);
    }

    // ---- store partials to wave-private slab (plain stores, no atomics) ----
    {
        float* cr = Cred[w];
#pragma unroll
        for (int reg = 0; reg < 4; ++reg) {
            const int row = quad * 4 + reg;    // C/D: col=lane&15, row=quad*4+reg
            cr[row * CRS +  0 + m] = a0[reg];
            cr[row * CRS + 16 + m] = a1[reg];
            cr[row * CRS + 32 + m] = a2[reg];
            cr[row * CRS + 48 + m] = a3[reg];
        }
    }
    __syncthreads();

    // ---- epilogue (first 4 waves): sum K-split, g=tanh, out = g @ Wout ----
    if (tid < 256) {
        const int mm = tid >> 4;         // batch row
        const int ob = (tid & 15) * 4;   // 4 o's per thread
        float r0 = 0.0f, r1 = 0.0f;
#pragma unroll
        for (int t2 = 0; t2 < 4; ++t2) {
            const int o = ob + t2;
            float s = 0.0f;
#pragma unroll
            for (int ww = 0; ww < NW; ++ww)
                s += Cred[ww][mm * CRS + o];
            const float g = fast_tanh(s);
            r0 = fmaf(g, Wout[o * NCLASS + 0], r0);
            r1 = fmaf(g, Wout[o * NCLASS + 1], r1);
        }
#pragma unroll
        for (int off = 8; off > 0; off >>= 1) {
            r0 += __shfl_down(r0, off, 16);
            r1 += __shfl_down(r1, off, 16);
        }
        if ((tid & 15) == 0) {
            outb[mm * NCLASS + 0] = r0;
            outb[mm * NCLASS + 1] = r1;
        }
    }
    __syncthreads();
    if (tid < MT * NCLASS)
        out[bb * NCLASS + tid] = outb[tid];   // coalesced 32-dword store
}

extern "C" void kernel_launch(void* const* d_in, const int* in_sizes, int n_in,
                              void* d_out, int out_size, void* d_ws, size_t ws_size,
                              hipStream_t stream) {
    const float* x    = (const float*)d_in[0];
    const float* Wx   = (const float*)d_in[1];
    const float* ax   = (const float*)d_in[2];
    const float* cx   = (const float*)d_in[3];
    // d_in[4..6] = Wh, ah, ch — dead (comb[:, :HIDDEN] == tanh(x_phi))
    const float* Wc   = (const float*)d_in[7];
    const float* ac   = (const float*)d_in[8];
    const float* cc   = (const float*)d_in[9];
    const float* Wout = (const float*)d_in[10];
    float* out  = (float*)d_out;
    ushort* Wp  = (ushort*)d_ws;    // 40960 bf16 = 80 KiB of the 256 MB ws

    prep_wb<<<dim3(KTOT * HIDDEN / 256), dim3(256), 0, stream>>>(Wc, Wp);
    kan_mfma<<<dim3(BATCH / MT), dim3(64, NW), 0, stream>>>(
        x, Wx, ax, cx, ac, cc, Wout, Wp, out);
}

// Round 7
// 84.157 us; speedup vs baseline: 1.2910x; 1.0017x over previous
//
#include <hip/hip_runtime.h>

#define HIDDEN 64
#define SEQLEN 96
#define NB 10
#define BATCH 16384
#define NCLASS 2
#define KTOT (HIDDEN * NB)   // 640
#define NKC (KTOT / 32)      // 20 K-chunks of 32
#define MT 16                // batch rows per block (one MFMA M-tile)
#define NW 5                 // waves per block = K-split factor
#define KCW (NKC / NW)       // 4 K-chunks per wave
#define HSS 17               // hs stride (16+1: kills 4-way quad conflict)
#define CRS 66               // Cred stride (64+2)

typedef __attribute__((ext_vector_type(8))) short bf16x8;
typedef __attribute__((ext_vector_type(4))) float f32x4;

__device__ __forceinline__ float fast_tanh(float x) {
    float e = __expf(x + x);
    float r = __builtin_amdgcn_rcpf(e + 1.0f);
    return fmaf(-2.0f, r, 1.0f);
}

__device__ __forceinline__ unsigned bf16_rn(float f) {
    unsigned u = __float_as_uint(f);
    return (u + 0x8000u) >> 16;
}

// Repack Wc (i,o,k) fp32 -> bf16 B-fragments in d_ws. Coalesced reads,
// scattered ushort writes (L2-absorbed). Layout:
// Wp[((kcg*4 + nt)*64 + lhi*16 + n)*8 + j], q=i*10+k: kcg=q>>5,
// lhi=(q>>3)&3, j=q&7; o: nt=o>>4, n=o&15.
__global__ __launch_bounds__(256) void prep_wb(const float* __restrict__ Wc,
                                               ushort* __restrict__ Wp) {
    const int e = blockIdx.x * 256 + threadIdx.x;   // 0..40959
    const float v = Wc[e];
    const int i   = e / 640;
    const int rem = e - i * 640;
    const int o   = rem / 10;
    const int k   = rem - o * 10;
    const int q   = i * NB + k;
    const int kcg = q >> 5, lhi = (q >> 3) & 3, j = q & 7;
    const int nt  = o >> 4, n = o & 15;
    Wp[(((kcg * 4 + nt) * 64) + lhi * 16 + n) * 8 + j] = (ushort)bf16_rn(v);
}

__global__ __launch_bounds__(64 * NW, 5) void kan_mfma(
    const float* __restrict__ x,    // (B, SEQLEN)
    const float* __restrict__ Wx,   // (1, HIDDEN, NB)
    const float* __restrict__ ax, const float* __restrict__ cx,  // (1, NB)
    const float* __restrict__ ac,   // (HIDDEN, NB) flat == q-order
    const float* __restrict__ cc,   // (HIDDEN, NB)
    const float* __restrict__ Wout, // (HIDDEN, NCLASS)
    const ushort* __restrict__ Wp,  // packed B-fragments (d_ws)
    float* __restrict__ out)        // (B, NCLASS)
{
    __shared__ float hs[65 * HSS];          // h[i][m] + guard row (4.4 KB)
    __shared__ float acs[KTOT], ccs[KTOT];  // staged ac/cc (5 KB)
    __shared__ float Cred[NW][MT * CRS];    // per-wave partials (21 KB)
    __shared__ float outb[MT * NCLASS];

    const int lane = threadIdx.x;    // 0..63
    const int w    = threadIdx.y;    // 0..4 (K-split wave id)
    const int tid  = w * 64 + lane;
    const int bb   = blockIdx.x * MT;

    // ---- stage ac/cc into LDS (coalesced float4; 1280 floats / 320 thr) ----
    if (tid < 160)
        *(float4*)&acs[tid * 4] = *(const float4*)&ac[tid * 4];
    else
        *(float4*)&ccs[(tid - 160) * 4] = *(const float4*)&cc[(tid - 160) * 4];

    // ---- stage A (first 4 waves): h from x[:,95]; recurrence is dead ----
    if (tid < 256) {
        const int sm = tid & 15;     // batch row
        const int sg = tid >> 4;     // 4 i's per thread
        const float u = x[(bb + sm) * SEQLEN + (SEQLEN - 1)];
        float t[NB];
#pragma unroll
        for (int k = 0; k < NB; ++k)
            t[k] = fast_tanh(fmaf(ax[k], u, cx[k]));
#pragma unroll
        for (int r = 0; r < 4; ++r) {
            const int i = sg * 4 + r;
            const float* wxr = Wx + i * NB;
            float hx = 0.0f;
#pragma unroll
            for (int k = 0; k < NB; ++k)
                hx = fmaf(wxr[k], t[k], hx);
            hs[i * HSS + sm] = fast_tanh(hx);
        }
    }
    __syncthreads();

    // ---- GEMM: wave w owns K-chunks [w*4, w*4+4), all 64 o.
    //      B-fragments software-pipelined: chunk c+1's global loads are in
    //      flight during chunk c's tanh/pack work. ac/cc/h come from LDS.
    const int m    = lane & 15;
    const int quad = lane >> 4;
    f32x4 a0 = {0,0,0,0}, a1 = {0,0,0,0}, a2 = {0,0,0,0}, a3 = {0,0,0,0};

    const int kcg0 = w * KCW;
    const ushort* wbase = Wp + (size_t)(kcg0 * 4) * 512 + lane * 8;
    bf16x8 nb0 = *(const bf16x8*)(wbase);
    bf16x8 nb1 = *(const bf16x8*)(wbase + 512);
    bf16x8 nb2 = *(const bf16x8*)(wbase + 1024);
    bf16x8 nb3 = *(const bf16x8*)(wbase + 1536);

#pragma unroll 1
    for (int c = 0; c < KCW; ++c) {
        const bf16x8 b0 = nb0, b1 = nb1, b2 = nb2, b3 = nb3;
        if (c + 1 < KCW) {               // prefetch next chunk's B-frags
            const ushort* wb2 = wbase + (c + 1) * 2048;
            nb0 = *(const bf16x8*)(wb2);
            nb1 = *(const bf16x8*)(wb2 + 512);
            nb2 = *(const bf16x8*)(wb2 + 1024);
            nb3 = *(const bf16x8*)(wb2 + 1536);
        }
        const int kcg = kcg0 + c;
        const int q0  = kcg * 32 + quad * 8;
        const int i0  = q0 / 10;         // magic-mul
        const int r0  = q0 - i0 * 10;
        const float h0 = hs[i0 * HSS + m];
        const float h1 = hs[(i0 + 1) * HSS + m];  // guard row; never OOB
        const float4 av0 = *(const float4*)&acs[q0];      // ds_read_b128,
        const float4 av1 = *(const float4*)&acs[q0 + 4];  // conflict-free
        const float4 cv0 = *(const float4*)&ccs[q0];
        const float4 cv1 = *(const float4*)&ccs[q0 + 4];

        const float av[8] = {av0.x,av0.y,av0.z,av0.w,av1.x,av1.y,av1.z,av1.w};
        const float cv[8] = {cv0.x,cv0.y,cv0.z,cv0.w,cv1.x,cv1.y,cv1.z,cv1.w};
        union { unsigned u[4]; bf16x8 v; } af;
#pragma unroll
        for (int jj = 0; jj < 4; ++jj) {
            const int j0 = 2 * jj, j1 = j0 + 1;
            const float hj0 = (r0 + j0 >= 10) ? h1 : h0;
            const float hj1 = (r0 + j1 >= 10) ? h1 : h0;
            const float p0 = fast_tanh(fmaf(av[j0], hj0, cv[j0]));
            const float p1 = fast_tanh(fmaf(av[j1], hj1, cv[j1]));
            af.u[jj] = bf16_rn(p0) | (bf16_rn(p1) << 16);
        }
        a0 = __builtin_amdgcn_mfma_f32_16x16x32_bf16(af.v, b0, a0, 0, 0, 0);
        a1 = __builtin_amdgcn_mfma_f32_16x16x32_bf16(af.v, b1, a1, 0, 0, 0);
        a2 = __builtin_amdgcn_mfma_f32_16x16x32_bf16(af.v, b2, a2, 0, 0, 0);
        a3 = __builtin_amdgcn_mfma_f32_16x16x32_bf16(af.v, b3, a3, 0, 0, 0);
    }

    // ---- store partials to wave-private slab (no atomics) ----
    {
        float* cr = Cred[w];
#pragma unroll
        for (int reg = 0; reg < 4; ++reg) {
            const int row = quad * 4 + reg;    // C/D: col=lane&15, row=quad*4+reg
            cr[row * CRS +  0 + m] = a0[reg];
            cr[row * CRS + 16 + m] = a1[reg];
            cr[row * CRS + 32 + m] = a2[reg];
            cr[row * CRS + 48 + m] = a3[reg];
        }
    }
    __syncthreads();

    // ---- epilogue (first 4 waves): sum K-split, g=tanh, out = g @ Wout ----
    if (tid < 256) {
        const int mm = tid >> 4;         // batch row
        const int ob = (tid & 15) * 4;   // 4 o's per thread
        float r0 = 0.0f, r1 = 0.0f;
#pragma unroll
        for (int t2 = 0; t2 < 4; ++t2) {
            const int o = ob + t2;
            float s = 0.0f;
#pragma unroll
            for (int ww = 0; ww < NW; ++ww)
                s += Cred[ww][mm * CRS + o];
            const float g = fast_tanh(s);
            r0 = fmaf(g, Wout[o * NCLASS + 0], r0);
            r1 = fmaf(g, Wout[o * NCLASS + 1], r1);
        }
#pragma unroll
        for (int off = 8; off > 0; off >>= 1) {
            r0 += __shfl_down(r0, off, 16);
            r1 += __shfl_down(r1, off, 16);
        }
        if ((tid & 15) == 0) {
            outb[mm * NCLASS + 0] = r0;
            outb[mm * NCLASS + 1] = r1;
        }
    }
    __syncthreads();
    if (tid < MT * NCLASS)
        out[bb * NCLASS + tid] = outb[tid];   // coalesced 32-dword store
}

extern "C" void kernel_launch(void* const* d_in, const int* in_sizes, int n_in,
                              void* d_out, int out_size, void* d_ws, size_t ws_size,
                              hipStream_t stream) {
    const float* x    = (const float*)d_in[0];
    const float* Wx   = (const float*)d_in[1];
    const float* ax   = (const float*)d_in[2];
    const float* cx   = (const float*)d_in[3];
    // d_in[4..6] = Wh, ah, ch — dead (comb[:, :HIDDEN] == tanh(x_phi))
    const float* Wc   = (const float*)d_in[7];
    const float* ac   = (const float*)d_in[8];
    const float* cc   = (const float*)d_in[9];
    const float* Wout = (const float*)d_in[10];
    float* out  = (float*)d_out;
    ushort* Wp  = (ushort*)d_ws;    // 40960 bf16 = 80 KiB of the 256 MB ws

    prep_wb<<<dim3(KTOT * HIDDEN / 256), dim3(256), 0, stream>>>(Wc, Wp);
    kan_mfma<<<dim3(BATCH / MT), dim3(64, NW), 0, stream>>>(
        x, Wx, ax, cx, ac, cc, Wout, Wp, out);
}